// Round 1
// baseline (503.343 us; speedup 1.0000x reference)
//
#include <hip/hip_runtime.h>
#include <hip/hip_bf16.h>

// MemoryEfficientMultiheadAttention: chunked (block-diagonal) MHA.
// S=4096, B=4, D=1024, H=16, dk=64, CHUNK=256.
// Pipeline: cvt weights -> QKV proj GEMMs (bf16 MFMA) -> per-chunk flash attn -> out proj.

namespace {

constexpr int kSeq = 4096, kB = 4, kDm = 1024, kNh = 16, kDk = 64, kChk = 256;
constexpr int kMr = kSeq * kB;       // 16384 GEMM rows
constexpr int kNchk = kSeq / kChk;   // 16 chunks

typedef __attribute__((ext_vector_type(8))) short bf16x8;
typedef __attribute__((ext_vector_type(4))) float f32x4;
typedef __attribute__((ext_vector_type(8))) unsigned short u16x8;
typedef __attribute__((ext_vector_type(4))) unsigned short u16x4;

__device__ __forceinline__ unsigned short f2bf(float x) {
  union { float f; unsigned u; } v; v.f = x;
  unsigned r = v.u + 0x7fffu + ((v.u >> 16) & 1u);   // RNE
  return (unsigned short)(r >> 16);
}
__device__ __forceinline__ float bf2f(unsigned short u) {
  union { unsigned u; float f; } v; v.u = ((unsigned)u) << 16;
  return v.f;
}
// XOR swizzle for 128B-row-stride LDS tiles: xor byte bits 4-6 with row&7.
__device__ __forceinline__ int swz(int bo) { return bo ^ ((bo >> 3) & 0x70); }

__global__ __launch_bounds__(256) void cvt_f32_bf16(const float* __restrict__ src,
                                                    unsigned short* __restrict__ dst,
                                                    int n4) {
  int i = blockIdx.x * 256 + threadIdx.x;
  if (i < n4) {
    f32x4 v = *(const f32x4*)(src + (size_t)i * 4);
    u16x4 o;
    o[0] = f2bf(v[0]); o[1] = f2bf(v[1]); o[2] = f2bf(v[2]); o[3] = f2bf(v[3]);
    *(u16x4*)(dst + (size_t)i * 4) = o;
  }
}

// C[M,N] = A[M,K] @ Bw[N,K]^T + bias.  128x128 tile, BK=32, 4 waves, 2-phase dbuf.
template <int A_F32, int OUT_F32>
__global__ __launch_bounds__(256) void gemm_bt(const void* __restrict__ Ap,
                                               const unsigned short* __restrict__ Bw,
                                               const float* __restrict__ bias,
                                               void* __restrict__ Cp,
                                               int M, int N, int K) {
  __shared__ unsigned short As[2][128 * 32];
  __shared__ unsigned short Bs[2][128 * 32];
  const int tid = (int)threadIdx.x;
  const int l = tid & 63;
  const int wbase = tid & ~63;               // wave id * 64 (uniform per wave)
  const int rb = (int)blockIdx.y * 128, cb = (int)blockIdx.x * 128;
  const int wr = ((tid >> 7) & 1) * 64;      // wave row quadrant
  const int wc = ((tid >> 6) & 1) * 64;      // wave col quadrant
  const int l15 = l & 15, l4 = l >> 4;

  f32x4 acc[4][4] = {};

  auto stage = [&](int buf, int k0) {
    if constexpr (A_F32) {
      // fp32 A: reg-stage + convert. 1024 float4 chunks: row=ci>>3, 8 chunks/row.
      const float* A = (const float*)Ap;
#pragma unroll
      for (int i = 0; i < 4; ++i) {
        int ci = tid + 256 * i;
        int r = ci >> 3, c4 = ci & 7;
        f32x4 v = *(const f32x4*)(A + (size_t)(rb + r) * K + (k0 + c4 * 4));
        u16x4 o;
        o[0] = f2bf(v[0]); o[1] = f2bf(v[1]); o[2] = f2bf(v[2]); o[3] = f2bf(v[3]);
        *(u16x4*)&As[buf][r * 32 + c4 * 4] = o;
      }
    } else {
      // bf16 A: async global->LDS, 16B/lane, linear dest.
      const unsigned short* A = (const unsigned short*)Ap;
#pragma unroll
      for (int i = 0; i < 2; ++i) {
        int ch = i * 256 + tid;                 // 512 16B chunks; row=ch>>2
        int r = ch >> 2, cc = ch & 3;
        const unsigned short* g = A + (size_t)(rb + r) * K + (k0 + cc * 8);
        __builtin_amdgcn_global_load_lds(
            (const __attribute__((address_space(1))) unsigned int*)g,
            (__attribute__((address_space(3))) unsigned int*)&As[buf][(i * 256 + wbase) * 8],
            16, 0, 0);
      }
    }
#pragma unroll
    for (int i = 0; i < 2; ++i) {
      int ch = i * 256 + tid;
      int r = ch >> 2, cc = ch & 3;
      const unsigned short* g = Bw + (size_t)(cb + r) * K + (k0 + cc * 8);
      __builtin_amdgcn_global_load_lds(
          (const __attribute__((address_space(1))) unsigned int*)g,
          (__attribute__((address_space(3))) unsigned int*)&Bs[buf][(i * 256 + wbase) * 8],
          16, 0, 0);
    }
  };

  stage(0, 0);
  __syncthreads();
  int cur = 0;
  const int nkt = K >> 5;
  for (int kt = 0; kt < nkt; ++kt) {
    if (kt + 1 < nkt) stage(cur ^ 1, (kt + 1) << 5);
    bf16x8 af[4], bfr[4];
#pragma unroll
    for (int m = 0; m < 4; ++m)
      af[m] = *(const bf16x8*)&As[cur][(wr + m * 16 + l15) * 32 + l4 * 8];
#pragma unroll
    for (int n = 0; n < 4; ++n)
      bfr[n] = *(const bf16x8*)&Bs[cur][(wc + n * 16 + l15) * 32 + l4 * 8];
#pragma unroll
    for (int m = 0; m < 4; ++m)
#pragma unroll
      for (int n = 0; n < 4; ++n)
        acc[m][n] = __builtin_amdgcn_mfma_f32_16x16x32_bf16(af[m], bfr[n], acc[m][n], 0, 0, 0);
    __syncthreads();
    cur ^= 1;
  }

  // Epilogue: C/D layout col=lane&15, row=(lane>>4)*4+reg (m89-verified).
#pragma unroll
  for (int n = 0; n < 4; ++n) {
    int col = cb + wc + n * 16 + l15;
    float bv = bias[col];
#pragma unroll
    for (int m = 0; m < 4; ++m) {
      int row0 = rb + wr + m * 16 + l4 * 4;
#pragma unroll
      for (int j = 0; j < 4; ++j) {
        float v = acc[m][n][j] + bv;
        if constexpr (OUT_F32)
          ((float*)Cp)[(size_t)(row0 + j) * N + col] = v;
        else
          ((unsigned short*)Cp)[(size_t)(row0 + j) * N + col] = f2bf(v);
      }
    }
  }
}

// Block-diagonal attention. One block per (b,h,chunk); 4 waves x 64 Q-rows.
// Online softmax over 4 KV-blocks of 64. All LDS tiles 128B-row-stride -> XOR swizzle.
__global__ __launch_bounds__(256) void attn_blkdiag(const unsigned short* __restrict__ qw,
                                                    const unsigned short* __restrict__ kw,
                                                    const unsigned short* __restrict__ vw,
                                                    unsigned short* __restrict__ ow) {
  __shared__ unsigned short Kl[64 * 64];       // [kv_row][d]      (swizzled)
  __shared__ unsigned short Vt[64 * 64];       // [d][kv_row]      (transposed, swizzled)
  __shared__ unsigned short Pl[4][64 * 64];    // per-wave P       (swizzled)
  const int tid = (int)threadIdx.x;
  const int w = tid >> 6, l = tid & 63;
  const int l15 = l & 15, l4 = l >> 4;
  const int bid = (int)blockIdx.x;
  const int c = bid & 15, h = (bid >> 4) & 15, b = bid >> 8;

  // Q fragments in registers, prescaled by 1/sqrt(dk)=0.125 (exact in bf16).
  bf16x8 q[4][2];
  const int qr0 = c * kChk + w * 64;
#pragma unroll
  for (int m = 0; m < 4; ++m)
#pragma unroll
    for (int kk = 0; kk < 2; ++kk) {
      int s = qr0 + m * 16 + l15;
      int d = kk * 32 + l4 * 8;
      u16x8 v = *(const u16x8*)(qw + (size_t)(s * kB + b) * kDm + h * kDk + d);
      u16x8 o;
#pragma unroll
      for (int j = 0; j < 8; ++j) o[j] = f2bf(bf2f(v[j]) * 0.125f);
      q[m][kk] = *(bf16x8*)&o;
    }

  float mst[4][4], lst[4][4];
#pragma unroll
  for (int m = 0; m < 4; ++m)
#pragma unroll
    for (int j = 0; j < 4; ++j) { mst[m][j] = -1e30f; lst[m][j] = 0.f; }
  f32x4 oacc[4][4] = {};

  for (int kb = 0; kb < 4; ++kb) {
    __syncthreads();   // previous iteration's K/Vt reads are done
    {
      int r = tid >> 2, c0 = (tid & 3) * 16;
      int s = c * kChk + kb * 64 + r;
      const unsigned short* ks = kw + (size_t)(s * kB + b) * kDm + h * kDk + c0;
      u16x8 k0v = *(const u16x8*)ks;
      u16x8 k1v = *(const u16x8*)(ks + 8);
      int bo = r * 128 + c0 * 2;
      *(u16x8*)((char*)Kl + swz(bo)) = k0v;
      *(u16x8*)((char*)Kl + swz(bo + 16)) = k1v;
      const unsigned short* vs = vw + (size_t)(s * kB + b) * kDm + h * kDk + c0;
      u16x8 v0 = *(const u16x8*)vs;
      u16x8 v1 = *(const u16x8*)(vs + 8);
#pragma unroll
      for (int j = 0; j < 8; ++j) {
        int b0 = (c0 + j) * 128 + r * 2;
        *(unsigned short*)((char*)Vt + swz(b0)) = v0[j];
        int b1 = (c0 + 8 + j) * 128 + r * 2;
        *(unsigned short*)((char*)Vt + swz(b1)) = v1[j];
      }
    }
    __syncthreads();

    // S = Q K^T  (64x64 per wave)
    f32x4 sacc[4][4] = {};
#pragma unroll
    for (int kk = 0; kk < 2; ++kk) {
      bf16x8 kf[4];
#pragma unroll
      for (int n = 0; n < 4; ++n) {
        int bo = (n * 16 + l15) * 128 + (kk * 32 + l4 * 8) * 2;
        kf[n] = *(const bf16x8*)((const char*)Kl + swz(bo));
      }
#pragma unroll
      for (int m = 0; m < 4; ++m)
#pragma unroll
        for (int n = 0; n < 4; ++n)
          sacc[m][n] = __builtin_amdgcn_mfma_f32_16x16x32_bf16(q[m][kk], kf[n], sacc[m][n], 0, 0, 0);
    }

    // Online softmax update; row r owned by 16 lanes (l>>4 fixed, l&15 varies).
#pragma unroll
    for (int m = 0; m < 4; ++m)
#pragma unroll
      for (int j = 0; j < 4; ++j) {
        float rm = fmaxf(fmaxf(sacc[m][0][j], sacc[m][1][j]),
                         fmaxf(sacc[m][2][j], sacc[m][3][j]));
#pragma unroll
        for (int off = 1; off < 16; off <<= 1) rm = fmaxf(rm, __shfl_xor(rm, off, 64));
        float mn = fmaxf(mst[m][j], rm);
        float corr = __expf(mst[m][j] - mn);
        mst[m][j] = mn;
        float rs = 0.f;
#pragma unroll
        for (int n = 0; n < 4; ++n) {
          float p = __expf(sacc[m][n][j] - mn);
          sacc[m][n][j] = p;
          rs += p;
        }
#pragma unroll
        for (int off = 1; off < 16; off <<= 1) rs += __shfl_xor(rs, off, 64);
        lst[m][j] = lst[m][j] * corr + rs;
#pragma unroll
        for (int n = 0; n < 4; ++n) oacc[m][n][j] *= corr;
      }

    // P (D-layout) -> LDS bf16 (swizzled), then re-read in A-frag layout.
    char* pb = (char*)Pl[w];
#pragma unroll
    for (int m = 0; m < 4; ++m)
#pragma unroll
      for (int n = 0; n < 4; ++n)
#pragma unroll
        for (int j = 0; j < 4; ++j) {
          int row = m * 16 + l4 * 4 + j;
          int bo = row * 128 + (n * 16 + l15) * 2;
          *(unsigned short*)(pb + swz(bo)) = f2bf(sacc[m][n][j]);
        }
    asm volatile("s_waitcnt lgkmcnt(0)" ::: "memory");

    // O += P @ V
#pragma unroll
    for (int kk = 0; kk < 2; ++kk) {
      bf16x8 pa[4], vf[4];
#pragma unroll
      for (int m = 0; m < 4; ++m) {
        int bo = (m * 16 + l15) * 128 + (kk * 32 + l4 * 8) * 2;
        pa[m] = *(const bf16x8*)(pb + swz(bo));
      }
#pragma unroll
      for (int n = 0; n < 4; ++n) {
        int bo = (n * 16 + l15) * 128 + (kk * 32 + l4 * 8) * 2;
        vf[n] = *(const bf16x8*)((const char*)Vt + swz(bo));
      }
#pragma unroll
      for (int m = 0; m < 4; ++m)
#pragma unroll
        for (int n = 0; n < 4; ++n)
          oacc[m][n] = __builtin_amdgcn_mfma_f32_16x16x32_bf16(pa[m], vf[n], oacc[m][n], 0, 0, 0);
    }
  }

  // Normalize + store bf16 to (S,B,D) layout.
#pragma unroll
  for (int m = 0; m < 4; ++m)
#pragma unroll
    for (int j = 0; j < 4; ++j) {
      float inv = 1.f / lst[m][j];
      int s = qr0 + m * 16 + l4 * 4 + j;
#pragma unroll
      for (int n = 0; n < 4; ++n) {
        int d = h * kDk + n * 16 + l15;
        ow[(size_t)(s * kB + b) * kDm + d] = f2bf(oacc[m][n][j] * inv);
      }
    }
}

}  // namespace

extern "C" void kernel_launch(void* const* d_in, const int* in_sizes, int n_in,
                              void* d_out, int out_size, void* d_ws, size_t ws_size,
                              hipStream_t stream) {
  const float* query = (const float*)d_in[0];
  const float* key   = (const float*)d_in[1];
  const float* value = (const float*)d_in[2];
  const float* Wq = (const float*)d_in[3];
  const float* bq = (const float*)d_in[4];
  const float* Wk = (const float*)d_in[5];
  const float* bk = (const float*)d_in[6];
  const float* Wv = (const float*)d_in[7];
  const float* bv = (const float*)d_in[8];
  const float* Wo = (const float*)d_in[9];
  const float* bo = (const float*)d_in[10];

  // ws layout (bf16): Wq|Wk|Wv|Wo (4x1M) then q|k|v|attn (4x16M) = 136 MB.
  const size_t needed = ((size_t)4 * kDm * kDm + (size_t)4 * kMr * kDm) * 2;
  if (ws_size < needed) return;  // visible as all-zero output
  unsigned short* wsp = (unsigned short*)d_ws;
  unsigned short* wqb = wsp;
  unsigned short* wkb = wqb + (size_t)kDm * kDm;
  unsigned short* wvb = wkb + (size_t)kDm * kDm;
  unsigned short* wob = wvb + (size_t)kDm * kDm;
  unsigned short* qws = wob + (size_t)kDm * kDm;
  unsigned short* kws = qws + (size_t)kMr * kDm;
  unsigned short* vws = kws + (size_t)kMr * kDm;
  unsigned short* aws = vws + (size_t)kMr * kDm;

  const int n4 = kDm * kDm / 4;
  cvt_f32_bf16<<<dim3(n4 / 256), dim3(256), 0, stream>>>(Wq, wqb, n4);
  cvt_f32_bf16<<<dim3(n4 / 256), dim3(256), 0, stream>>>(Wk, wkb, n4);
  cvt_f32_bf16<<<dim3(n4 / 256), dim3(256), 0, stream>>>(Wv, wvb, n4);
  cvt_f32_bf16<<<dim3(n4 / 256), dim3(256), 0, stream>>>(Wo, wob, n4);

  dim3 gg(kDm / 128, kMr / 128);  // (8, 128)
  gemm_bt<1, 0><<<gg, 256, 0, stream>>>(query, wqb, bq, qws, kMr, kDm, kDm);
  gemm_bt<1, 0><<<gg, 256, 0, stream>>>(key,   wkb, bk, kws, kMr, kDm, kDm);
  gemm_bt<1, 0><<<gg, 256, 0, stream>>>(value, wvb, bv, vws, kMr, kDm, kDm);

  attn_blkdiag<<<dim3(kB * kNh * kNchk), 256, 0, stream>>>(qws, kws, vws, aws);

  gemm_bt<0, 1><<<gg, 256, 0, stream>>>(aws, wob, bo, d_out, kMr, kDm, kDm);
}

// Round 2
// 463.765 us; speedup vs baseline: 1.0853x; 1.0853x over previous
//
#include <hip/hip_runtime.h>
#include <hip/hip_bf16.h>

// MemoryEfficientMultiheadAttention: chunked (block-diagonal) MHA.
// S=4096, B=4, D=1024, H=16, dk=64, CHUNK=256.
// Pipeline: cvt weights -> QKV proj GEMMs (head-major out) -> per-chunk flash attn
//           (coalesced, reg-prefetched KV) -> out proj (head-major A).

namespace {

constexpr int kSeq = 4096, kB = 4, kDm = 1024, kNh = 16, kDk = 64, kChk = 256;
constexpr int kMr = kSeq * kB;       // 16384 GEMM rows
constexpr int kNchk = kSeq / kChk;   // 16 chunks

typedef __attribute__((ext_vector_type(8))) short bf16x8;
typedef __attribute__((ext_vector_type(4))) float f32x4;
typedef __attribute__((ext_vector_type(8))) unsigned short u16x8;
typedef __attribute__((ext_vector_type(4))) unsigned short u16x4;

__device__ __forceinline__ unsigned short f2bf(float x) {
  union { float f; unsigned u; } v; v.f = x;
  unsigned r = v.u + 0x7fffu + ((v.u >> 16) & 1u);   // RNE
  return (unsigned short)(r >> 16);
}
// XOR swizzle for 128B-row-stride LDS tiles: xor byte bits 4-6 with row&7.
__device__ __forceinline__ int swz(int bo) { return bo ^ ((bo >> 3) & 0x70); }

// All four 1024x1024 weights -> bf16, dst contiguous (Wq|Wk|Wv|Wo).
__global__ __launch_bounds__(256) void cvt4(const float* __restrict__ s0,
                                            const float* __restrict__ s1,
                                            const float* __restrict__ s2,
                                            const float* __restrict__ s3,
                                            unsigned short* __restrict__ dst) {
  int i = blockIdx.x * 256 + threadIdx.x;          // 0 .. 4*2^18-1
  int t = i >> 18;
  int j = i & 0x3ffff;
  const float* s = (t == 0) ? s0 : (t == 1) ? s1 : (t == 2) ? s2 : s3;
  f32x4 v = *(const f32x4*)(s + (size_t)j * 4);
  u16x4 o;
  o[0] = f2bf(v[0]); o[1] = f2bf(v[1]); o[2] = f2bf(v[2]); o[3] = f2bf(v[3]);
  *(u16x4*)(dst + (size_t)i * 4) = o;
}

// C = A @ Bw^T + bias. 128x128 tile, BK=32, 4 waves, 2-phase dbuf, XCD-swizzled grid.
// ALAY: 1 = A fp32 row-major (M,K);  2 = A bf16 head-major (B,H,S,dk), rows t=s*kB+b.
// OHM:  1 = out bf16 head-major, scaled;  0 = out fp32 row-major (M,N).
template <int ALAY, int OHM>
__global__ __launch_bounds__(256) void gemm_bt(const void* __restrict__ Ap,
                                               const unsigned short* __restrict__ Bw,
                                               const float* __restrict__ bias,
                                               void* __restrict__ Cp, float scale) {
  constexpr int K = kDm, N = kDm;
  __shared__ unsigned short As[2][128 * 32];
  __shared__ unsigned short Bs[2][128 * 32];
  const int tid = (int)threadIdx.x;
  const int l = tid & 63;
  const int wbase = tid & ~63;               // wave id * 64 (uniform per wave)
  // bijective XCD swizzle: 1024 wgs % 8 == 0
  const int bid = (int)blockIdx.x;
  const int lin = (bid & 7) * 128 + (bid >> 3);
  const int rb = (lin >> 3) * 128, cb = (lin & 7) * 128;
  const int wr = ((tid >> 7) & 1) * 64;      // wave row quadrant
  const int wc = ((tid >> 6) & 1) * 64;      // wave col quadrant
  const int l15 = l & 15, l4 = l >> 4;

  f32x4 acc[4][4] = {};

  auto stage = [&](int buf, int k0) {
    if constexpr (ALAY == 1) {
      // fp32 A: reg-stage + convert. 1024 float4 chunks: row=ci>>3, 8 chunks/row.
      const float* A = (const float*)Ap;
#pragma unroll
      for (int i = 0; i < 4; ++i) {
        int ci = tid + 256 * i;
        int rr = ci >> 3, c4 = ci & 7;
        f32x4 v = *(const f32x4*)(A + (size_t)(rb + rr) * K + (k0 + c4 * 4));
        u16x4 o;
        o[0] = f2bf(v[0]); o[1] = f2bf(v[1]); o[2] = f2bf(v[2]); o[3] = f2bf(v[3]);
        *(u16x4*)&As[buf][rr * 32 + c4 * 4] = o;
      }
    } else {
      // bf16 head-major A: async global->LDS, 16B/lane, linear dest.
      const unsigned short* A = (const unsigned short*)Ap;
      int h = k0 >> 6, d0 = k0 & 63;
#pragma unroll
      for (int i = 0; i < 2; ++i) {
        int ch = i * 256 + tid;                 // 512 16B chunks; row=ch>>2
        int rr = ch >> 2, cc = ch & 3;
        int t = rb + rr; int s = t >> 2, b2 = t & 3;
        const unsigned short* g =
            A + ((size_t)(b2 * kNh + h) * kSeq + s) * kDk + d0 + cc * 8;
        __builtin_amdgcn_global_load_lds(
            (const __attribute__((address_space(1))) unsigned int*)g,
            (__attribute__((address_space(3))) unsigned int*)&As[buf][(i * 256 + wbase) * 8],
            16, 0, 0);
      }
    }
#pragma unroll
    for (int i = 0; i < 2; ++i) {
      int ch = i * 256 + tid;
      int rr = ch >> 2, cc = ch & 3;
      const unsigned short* g = Bw + (size_t)(cb + rr) * K + (k0 + cc * 8);
      __builtin_amdgcn_global_load_lds(
          (const __attribute__((address_space(1))) unsigned int*)g,
          (__attribute__((address_space(3))) unsigned int*)&Bs[buf][(i * 256 + wbase) * 8],
          16, 0, 0);
    }
  };

  stage(0, 0);
  __syncthreads();
  int cur = 0;
  constexpr int nkt = K >> 5;
  for (int kt = 0; kt < nkt; ++kt) {
    if (kt + 1 < nkt) stage(cur ^ 1, (kt + 1) << 5);
    bf16x8 af[4], bfr[4];
#pragma unroll
    for (int m = 0; m < 4; ++m)
      af[m] = *(const bf16x8*)&As[cur][(wr + m * 16 + l15) * 32 + l4 * 8];
#pragma unroll
    for (int n = 0; n < 4; ++n)
      bfr[n] = *(const bf16x8*)&Bs[cur][(wc + n * 16 + l15) * 32 + l4 * 8];
#pragma unroll
    for (int m = 0; m < 4; ++m)
#pragma unroll
      for (int n = 0; n < 4; ++n)
        acc[m][n] = __builtin_amdgcn_mfma_f32_16x16x32_bf16(af[m], bfr[n], acc[m][n], 0, 0, 0);
    __syncthreads();
    cur ^= 1;
  }

  // Epilogue: C/D layout col=lane&15, row=(lane>>4)*4+reg.
#pragma unroll
  for (int n = 0; n < 4; ++n) {
    int col = cb + wc + n * 16 + l15;
    float bv = bias[col];
    int h = col >> 6, dd = col & 63;
#pragma unroll
    for (int m = 0; m < 4; ++m) {
      int row0 = rb + wr + m * 16 + l4 * 4;
#pragma unroll
      for (int j = 0; j < 4; ++j) {
        float v = acc[m][n][j] + bv;
        int t = row0 + j;
        if constexpr (OHM) {
          int s = t >> 2, b2 = t & 3;
          ((unsigned short*)Cp)[((size_t)(b2 * kNh + h) * kSeq + s) * kDk + dd] =
              f2bf(v * scale);
        } else {
          ((float*)Cp)[(size_t)t * N + col] = v;
        }
      }
    }
  }
}

// Block-diagonal attention, head-major (B*H, S, dk) in/out.
// One block per (bh, chunk); 4 waves x 64 Q-rows; KV blocks of 64 with reg prefetch.
__global__ __launch_bounds__(256) void attn_blkdiag(const unsigned short* __restrict__ qw,
                                                    const unsigned short* __restrict__ kw,
                                                    const unsigned short* __restrict__ vw,
                                                    unsigned short* __restrict__ ow) {
  __shared__ unsigned short Kl[64 * 64];       // [kv_row][d]      (swizzled)
  __shared__ unsigned short Vt[64 * 64];       // [d][kv_row]      (transposed, swizzled)
  __shared__ unsigned short Pl[4][64 * 64];    // per-wave P       (swizzled)
  const int tid = (int)threadIdx.x;
  const int w = tid >> 6, l = tid & 63;
  const int l15 = l & 15, l4 = l >> 4;
  const int bid = (int)blockIdx.x;
  const int c = bid & 15, bh = bid >> 4;
  const size_t base = ((size_t)bh * kSeq + c * kChk) * kDk;
  const unsigned short* qp = qw + base;
  const unsigned short* kp = kw + base;
  const unsigned short* vp = vw + base;

  // Q fragments in registers (scale already folded into Q projection).
  bf16x8 q[4][2];
#pragma unroll
  for (int m = 0; m < 4; ++m)
#pragma unroll
    for (int kk = 0; kk < 2; ++kk)
      q[m][kk] = *(const bf16x8*)(qp + (w * 64 + m * 16 + l15) * 64 + kk * 32 + l4 * 8);

  float mst[4][4], lst[4][4];
#pragma unroll
  for (int m = 0; m < 4; ++m)
#pragma unroll
    for (int j = 0; j < 4; ++j) { mst[m][j] = -1e30f; lst[m][j] = 0.f; }
  f32x4 oacc[4][4] = {};

  // Coalesced KV prefetch: each thread owns 32B (=2x16B) of the contiguous 8KB tile.
  const int r = tid >> 2, c0 = (tid & 3) * 16;
  u16x8 kr0, kr1, vr0, vr1;
  {
    const unsigned short* kt = kp + tid * 16;
    kr0 = *(const u16x8*)kt; kr1 = *(const u16x8*)(kt + 8);
    const unsigned short* vt = vp + tid * 16;
    vr0 = *(const u16x8*)vt; vr1 = *(const u16x8*)(vt + 8);
  }

  for (int kb = 0; kb < 4; ++kb) {
    __syncthreads();   // previous iteration's K/Vt reads are done
    {
      int bo = r * 128 + c0 * 2;
      *(u16x8*)((char*)Kl + swz(bo)) = kr0;
      *(u16x8*)((char*)Kl + swz(bo + 16)) = kr1;
#pragma unroll
      for (int j = 0; j < 8; ++j) {
        *(unsigned short*)((char*)Vt + swz((c0 + j) * 128 + r * 2)) = vr0[j];
        *(unsigned short*)((char*)Vt + swz((c0 + 8 + j) * 128 + r * 2)) = vr1[j];
      }
    }
    __syncthreads();
    if (kb < 3) {   // T14: issue next-tile loads; latency hides under compute below
      const unsigned short* kt = kp + (kb + 1) * (64 * kDk) + tid * 16;
      kr0 = *(const u16x8*)kt; kr1 = *(const u16x8*)(kt + 8);
      const unsigned short* vt = vp + (kb + 1) * (64 * kDk) + tid * 16;
      vr0 = *(const u16x8*)vt; vr1 = *(const u16x8*)(vt + 8);
    }

    // S = Q K^T  (64x64 per wave)
    f32x4 sacc[4][4] = {};
#pragma unroll
    for (int kk = 0; kk < 2; ++kk) {
      bf16x8 kf[4];
#pragma unroll
      for (int n = 0; n < 4; ++n) {
        int bo = (n * 16 + l15) * 128 + (kk * 32 + l4 * 8) * 2;
        kf[n] = *(const bf16x8*)((const char*)Kl + swz(bo));
      }
#pragma unroll
      for (int m = 0; m < 4; ++m)
#pragma unroll
        for (int n = 0; n < 4; ++n)
          sacc[m][n] = __builtin_amdgcn_mfma_f32_16x16x32_bf16(q[m][kk], kf[n], sacc[m][n], 0, 0, 0);
    }

    // Online softmax; row owned by 16 lanes (l>>4 fixed per row-group).
#pragma unroll
    for (int m = 0; m < 4; ++m)
#pragma unroll
      for (int j = 0; j < 4; ++j) {
        float rm = fmaxf(fmaxf(sacc[m][0][j], sacc[m][1][j]),
                         fmaxf(sacc[m][2][j], sacc[m][3][j]));
#pragma unroll
        for (int off = 1; off < 16; off <<= 1) rm = fmaxf(rm, __shfl_xor(rm, off, 64));
        float mn = fmaxf(mst[m][j], rm);
        float corr = __expf(mst[m][j] - mn);
        mst[m][j] = mn;
        float rs = 0.f;
#pragma unroll
        for (int n = 0; n < 4; ++n) {
          float p = __expf(sacc[m][n][j] - mn);
          sacc[m][n][j] = p;
          rs += p;
        }
#pragma unroll
        for (int off = 1; off < 16; off <<= 1) rs += __shfl_xor(rs, off, 64);
        lst[m][j] = lst[m][j] * corr + rs;
#pragma unroll
        for (int n = 0; n < 4; ++n) oacc[m][n][j] *= corr;
      }

    // P (D-layout) -> LDS bf16 (swizzled, wave-private), re-read in A-frag layout.
    char* pb = (char*)Pl[w];
#pragma unroll
    for (int m = 0; m < 4; ++m)
#pragma unroll
      for (int n = 0; n < 4; ++n)
#pragma unroll
        for (int j = 0; j < 4; ++j) {
          int row = m * 16 + l4 * 4 + j;
          int bo = row * 128 + (n * 16 + l15) * 2;
          *(unsigned short*)(pb + swz(bo)) = f2bf(sacc[m][n][j]);
        }
    asm volatile("s_waitcnt lgkmcnt(0)" ::: "memory");

    // O += P @ V
#pragma unroll
    for (int kk = 0; kk < 2; ++kk) {
      bf16x8 pa[4], vf[4];
#pragma unroll
      for (int m = 0; m < 4; ++m) {
        int bo = (m * 16 + l15) * 128 + (kk * 32 + l4 * 8) * 2;
        pa[m] = *(const bf16x8*)(pb + swz(bo));
      }
#pragma unroll
      for (int n = 0; n < 4; ++n) {
        int bo = (n * 16 + l15) * 128 + (kk * 32 + l4 * 8) * 2;
        vf[n] = *(const bf16x8*)((const char*)Vt + swz(bo));
      }
#pragma unroll
      for (int m = 0; m < 4; ++m)
#pragma unroll
        for (int n = 0; n < 4; ++n)
          oacc[m][n] = __builtin_amdgcn_mfma_f32_16x16x32_bf16(pa[m], vf[n], oacc[m][n], 0, 0, 0);
    }
  }

  // Normalize + store bf16, head-major.
#pragma unroll
  for (int m = 0; m < 4; ++m)
#pragma unroll
    for (int j = 0; j < 4; ++j) {
      float inv = 1.f / lst[m][j];
      int srow = w * 64 + m * 16 + l4 * 4 + j;
#pragma unroll
      for (int n = 0; n < 4; ++n)
        ow[base + (size_t)srow * 64 + n * 16 + l15] = f2bf(oacc[m][n][j] * inv);
    }
}

}  // namespace

extern "C" void kernel_launch(void* const* d_in, const int* in_sizes, int n_in,
                              void* d_out, int out_size, void* d_ws, size_t ws_size,
                              hipStream_t stream) {
  const float* query = (const float*)d_in[0];
  const float* key   = (const float*)d_in[1];
  const float* value = (const float*)d_in[2];
  const float* Wq = (const float*)d_in[3];
  const float* bq = (const float*)d_in[4];
  const float* Wk = (const float*)d_in[5];
  const float* bk = (const float*)d_in[6];
  const float* Wv = (const float*)d_in[7];
  const float* bv = (const float*)d_in[8];
  const float* Wo = (const float*)d_in[9];
  const float* bo = (const float*)d_in[10];

  // ws layout (bf16): Wq|Wk|Wv|Wo (4x1M) then q|k|v|attn (4x16M) = 136 MB.
  const size_t needed = ((size_t)4 * kDm * kDm + (size_t)4 * kMr * kDm) * 2;
  if (ws_size < needed) return;
  unsigned short* wsp = (unsigned short*)d_ws;
  unsigned short* wqb = wsp;
  unsigned short* wkb = wqb + (size_t)kDm * kDm;
  unsigned short* wvb = wkb + (size_t)kDm * kDm;
  unsigned short* wob = wvb + (size_t)kDm * kDm;
  unsigned short* qws = wob + (size_t)kDm * kDm;
  unsigned short* kws = qws + (size_t)kMr * kDm;
  unsigned short* vws = kws + (size_t)kMr * kDm;
  unsigned short* aws = vws + (size_t)kMr * kDm;

  cvt4<<<dim3(4096), dim3(256), 0, stream>>>(Wq, Wk, Wv, Wo, wqb);

  gemm_bt<1, 1><<<dim3(1024), 256, 0, stream>>>(query, wqb, bq, qws, 0.125f);
  gemm_bt<1, 1><<<dim3(1024), 256, 0, stream>>>(key,   wkb, bk, kws, 1.0f);
  gemm_bt<1, 1><<<dim3(1024), 256, 0, stream>>>(value, wvb, bv, vws, 1.0f);

  attn_blkdiag<<<dim3(kB * kNh * kNchk), 256, 0, stream>>>(qws, kws, vws, aws);

  gemm_bt<2, 0><<<dim3(1024), 256, 0, stream>>>(aws, wob, bo, d_out, 1.0f);
}

// Round 3
// 369.176 us; speedup vs baseline: 1.3634x; 1.2562x over previous
//
#include <hip/hip_runtime.h>
#include <hip/hip_bf16.h>

// MemoryEfficientMultiheadAttention: chunked (block-diagonal) MHA.
// S=4096, B=4, D=1024, H=16, dk=64, CHUNK=256.
// cvt(weights,qkv->bf16) -> QKV GEMMs (head-major out, exp2-scaled Q)
//   -> flash attn (32 rows/wave, 2 blocks/chunk, 2 waves/SIMD) -> out proj.

namespace {

constexpr int kSeq = 4096, kB = 4, kDm = 1024, kNh = 16, kDk = 64, kChk = 256;
constexpr int kMr = kSeq * kB;       // 16384 GEMM rows
constexpr float kLog2e = 1.44269504088896340736f;

typedef __attribute__((ext_vector_type(8))) short bf16x8;
typedef __attribute__((ext_vector_type(4))) float f32x4;
typedef __attribute__((ext_vector_type(8))) unsigned short u16x8;
typedef __attribute__((ext_vector_type(4))) unsigned short u16x4;

__device__ __forceinline__ unsigned short f2bf(float x) {
  union { float f; unsigned u; } v; v.f = x;
  unsigned r = v.u + 0x7fffu + ((v.u >> 16) & 1u);   // RNE
  return (unsigned short)(r >> 16);
}
// XOR swizzle for 128B-row-stride LDS tiles: xor byte bits 4-6 with row&7.
__device__ __forceinline__ int swz(int bo) { return bo ^ ((bo >> 3) & 0x70); }

// All four 1024x1024 weights -> bf16, dst contiguous (Wq|Wk|Wv|Wo).
__global__ __launch_bounds__(256) void cvt4(const float* __restrict__ s0,
                                            const float* __restrict__ s1,
                                            const float* __restrict__ s2,
                                            const float* __restrict__ s3,
                                            unsigned short* __restrict__ dst) {
  int i = blockIdx.x * 256 + threadIdx.x;          // 0 .. 4*2^18-1
  int t = i >> 18;
  int j = i & 0x3ffff;
  const float* s = (t == 0) ? s0 : (t == 1) ? s1 : (t == 2) ? s2 : s3;
  f32x4 v = *(const f32x4*)(s + (size_t)j * 4);
  u16x4 o;
  o[0] = f2bf(v[0]); o[1] = f2bf(v[1]); o[2] = f2bf(v[2]); o[3] = f2bf(v[3]);
  *(u16x4*)(dst + (size_t)i * 4) = o;
}

// fp32 -> bf16 row-major copy (16384x1024), one f32x4 per thread.
__global__ __launch_bounds__(256) void cvt_rm(const float* __restrict__ src,
                                              unsigned short* __restrict__ dst) {
  size_t i = (size_t)blockIdx.x * 256 + threadIdx.x;   // 2^22 chunks
  f32x4 v = *(const f32x4*)(src + i * 4);
  u16x4 o;
  o[0] = f2bf(v[0]); o[1] = f2bf(v[1]); o[2] = f2bf(v[2]); o[3] = f2bf(v[3]);
  *(u16x4*)(dst + i * 4) = o;
}

// C = A @ Bw^T + bias. 128x128 tile, BK=32, 4 waves, 2-phase dbuf, XCD-swizzled grid.
// ALAY: 0 = A bf16 row-major (M,K) via global_load_lds
//       1 = A fp32 row-major (reg-staged + cvt)
//       2 = A bf16 head-major (B,H,S,dk), rows t=s*kB+b
// OHM:  1 = out bf16 head-major, scaled;  0 = out fp32 row-major (M,N).
template <int ALAY, int OHM>
__global__ __launch_bounds__(256) void gemm_bt(const void* __restrict__ Ap,
                                               const unsigned short* __restrict__ Bw,
                                               const float* __restrict__ bias,
                                               void* __restrict__ Cp, float scale) {
  constexpr int K = kDm, N = kDm;
  __shared__ unsigned short As[2][128 * 32];
  __shared__ unsigned short Bs[2][128 * 32];
  const int tid = (int)threadIdx.x;
  const int l = tid & 63;
  const int wbase = tid & ~63;               // wave id * 64 (uniform per wave)
  // bijective XCD swizzle: 1024 wgs % 8 == 0
  const int bid = (int)blockIdx.x;
  const int lin = (bid & 7) * 128 + (bid >> 3);
  const int rb = (lin >> 3) * 128, cb = (lin & 7) * 128;
  const int wr = ((tid >> 7) & 1) * 64;      // wave row quadrant
  const int wc = ((tid >> 6) & 1) * 64;      // wave col quadrant
  const int l15 = l & 15, l4 = l >> 4;

  f32x4 acc[4][4] = {};

  auto stage = [&](int buf, int k0) {
    if constexpr (ALAY == 0) {
      const unsigned short* A = (const unsigned short*)Ap;
#pragma unroll
      for (int i = 0; i < 2; ++i) {
        int ch = i * 256 + tid;                 // 512 16B chunks; row=ch>>2
        int rr = ch >> 2, cc = ch & 3;
        const unsigned short* g = A + (size_t)(rb + rr) * K + (k0 + cc * 8);
        __builtin_amdgcn_global_load_lds(
            (const __attribute__((address_space(1))) unsigned int*)g,
            (__attribute__((address_space(3))) unsigned int*)&As[buf][(i * 256 + wbase) * 8],
            16, 0, 0);
      }
    } else if constexpr (ALAY == 1) {
      const float* A = (const float*)Ap;
#pragma unroll
      for (int i = 0; i < 4; ++i) {
        int ci = tid + 256 * i;
        int rr = ci >> 3, c4 = ci & 7;
        f32x4 v = *(const f32x4*)(A + (size_t)(rb + rr) * K + (k0 + c4 * 4));
        u16x4 o;
        o[0] = f2bf(v[0]); o[1] = f2bf(v[1]); o[2] = f2bf(v[2]); o[3] = f2bf(v[3]);
        *(u16x4*)&As[buf][rr * 32 + c4 * 4] = o;
      }
    } else {
      // bf16 head-major A: async global->LDS, 16B/lane, linear dest.
      const unsigned short* A = (const unsigned short*)Ap;
      int h = k0 >> 6, d0 = k0 & 63;
#pragma unroll
      for (int i = 0; i < 2; ++i) {
        int ch = i * 256 + tid;
        int rr = ch >> 2, cc = ch & 3;
        int t = rb + rr; int s = t >> 2, b2 = t & 3;
        const unsigned short* g =
            A + ((size_t)(b2 * kNh + h) * kSeq + s) * kDk + d0 + cc * 8;
        __builtin_amdgcn_global_load_lds(
            (const __attribute__((address_space(1))) unsigned int*)g,
            (__attribute__((address_space(3))) unsigned int*)&As[buf][(i * 256 + wbase) * 8],
            16, 0, 0);
      }
    }
#pragma unroll
    for (int i = 0; i < 2; ++i) {
      int ch = i * 256 + tid;
      int rr = ch >> 2, cc = ch & 3;
      const unsigned short* g = Bw + (size_t)(cb + rr) * K + (k0 + cc * 8);
      __builtin_amdgcn_global_load_lds(
          (const __attribute__((address_space(1))) unsigned int*)g,
          (__attribute__((address_space(3))) unsigned int*)&Bs[buf][(i * 256 + wbase) * 8],
          16, 0, 0);
    }
  };

  stage(0, 0);
  __syncthreads();
  int cur = 0;
  constexpr int nkt = K >> 5;
  for (int kt = 0; kt < nkt; ++kt) {
    if (kt + 1 < nkt) stage(cur ^ 1, (kt + 1) << 5);
    bf16x8 af[4], bfr[4];
#pragma unroll
    for (int m = 0; m < 4; ++m)
      af[m] = *(const bf16x8*)&As[cur][(wr + m * 16 + l15) * 32 + l4 * 8];
#pragma unroll
    for (int n = 0; n < 4; ++n)
      bfr[n] = *(const bf16x8*)&Bs[cur][(wc + n * 16 + l15) * 32 + l4 * 8];
#pragma unroll
    for (int m = 0; m < 4; ++m)
#pragma unroll
      for (int n = 0; n < 4; ++n)
        acc[m][n] = __builtin_amdgcn_mfma_f32_16x16x32_bf16(af[m], bfr[n], acc[m][n], 0, 0, 0);
    __syncthreads();
    cur ^= 1;
  }

  // Epilogue: C/D layout col=lane&15, row=(lane>>4)*4+reg.
#pragma unroll
  for (int n = 0; n < 4; ++n) {
    int col = cb + wc + n * 16 + l15;
    float bv = bias[col];
    int h = col >> 6, dd = col & 63;
#pragma unroll
    for (int m = 0; m < 4; ++m) {
      int row0 = rb + wr + m * 16 + l4 * 4;
#pragma unroll
      for (int j = 0; j < 4; ++j) {
        float v = acc[m][n][j] + bv;
        int t = row0 + j;
        if constexpr (OHM) {
          int s = t >> 2, b2 = t & 3;
          ((unsigned short*)Cp)[((size_t)(b2 * kNh + h) * kSeq + s) * kDk + dd] =
              f2bf(v * scale);
        } else {
          ((float*)Cp)[(size_t)t * N + col] = v;
        }
      }
    }
  }
}

// Block-diagonal flash attention, head-major (B*H, S, dk) in/out.
// Grid 2048: one block per (bh, chunk, half); 4 waves x 32 Q-rows.
// Softmax in exp2 domain (log2e folded into Q projection scale).
__global__ __launch_bounds__(256) void attn_blkdiag(const unsigned short* __restrict__ qw,
                                                    const unsigned short* __restrict__ kw,
                                                    const unsigned short* __restrict__ vw,
                                                    unsigned short* __restrict__ ow) {
  __shared__ unsigned short Kl[64 * 64];       // [kv_row][d]   (swizzled)
  __shared__ unsigned short Vt[64 * 64];       // [d][kv_row]   (transposed, swizzled)
  __shared__ unsigned short Pl[4][32 * 64];    // per-wave P    (swizzled)
  const int tid = (int)threadIdx.x;
  const int w = tid >> 6, l = tid & 63;
  const int l15 = l & 15, l4 = l >> 4;
  // XCD swizzle (2048 % 8 == 0): chunk-halves sharing K/V land on one XCD.
  const int bid0 = (int)blockIdx.x;
  const int bid = (bid0 & 7) * 256 + (bid0 >> 3);
  const int hf = bid & 1, c = (bid >> 1) & 15, bh = bid >> 5;
  const size_t base = ((size_t)bh * kSeq + c * kChk) * kDk;
  const unsigned short* qp = qw + base + (size_t)hf * 128 * kDk;
  const unsigned short* kp = kw + base;
  const unsigned short* vp = vw + base;

  // Q fragments in registers (scale folded into Q projection).
  bf16x8 q[2][2];
#pragma unroll
  for (int m = 0; m < 2; ++m)
#pragma unroll
    for (int kk = 0; kk < 2; ++kk)
      q[m][kk] = *(const bf16x8*)(qp + (w * 32 + m * 16 + l15) * 64 + kk * 32 + l4 * 8);

  float mst[2][4], lst[2][4];
#pragma unroll
  for (int m = 0; m < 2; ++m)
#pragma unroll
    for (int j = 0; j < 4; ++j) { mst[m][j] = -1e30f; lst[m][j] = 0.f; }
  f32x4 oacc[2][4] = {};

  // Coalesced KV prefetch: each thread owns 32B of the contiguous 8KB tile.
  const int r = tid >> 2, c0 = (tid & 3) * 16;
  u16x8 kr0, kr1, vr0, vr1;
  {
    const unsigned short* kt = kp + tid * 16;
    kr0 = *(const u16x8*)kt; kr1 = *(const u16x8*)(kt + 8);
    const unsigned short* vt = vp + tid * 16;
    vr0 = *(const u16x8*)vt; vr1 = *(const u16x8*)(vt + 8);
  }

  for (int kb = 0; kb < 4; ++kb) {
    __syncthreads();   // previous iteration's K/Vt reads are done
    {
      int bo = r * 128 + c0 * 2;
      *(u16x8*)((char*)Kl + swz(bo)) = kr0;
      *(u16x8*)((char*)Kl + swz(bo + 16)) = kr1;
#pragma unroll
      for (int j = 0; j < 8; ++j) {
        *(unsigned short*)((char*)Vt + swz((c0 + j) * 128 + r * 2)) = vr0[j];
        *(unsigned short*)((char*)Vt + swz((c0 + 8 + j) * 128 + r * 2)) = vr1[j];
      }
    }
    __syncthreads();
    if (kb < 3) {   // T14: issue next-tile loads; latency hides under compute
      const unsigned short* kt = kp + (kb + 1) * (64 * kDk) + tid * 16;
      kr0 = *(const u16x8*)kt; kr1 = *(const u16x8*)(kt + 8);
      const unsigned short* vt = vp + (kb + 1) * (64 * kDk) + tid * 16;
      vr0 = *(const u16x8*)vt; vr1 = *(const u16x8*)(vt + 8);
    }

    // S = Q K^T  (32x64 per wave)
    f32x4 sacc[2][4] = {};
#pragma unroll
    for (int kk = 0; kk < 2; ++kk) {
      bf16x8 kf[4];
#pragma unroll
      for (int n = 0; n < 4; ++n) {
        int bo = (n * 16 + l15) * 128 + (kk * 32 + l4 * 8) * 2;
        kf[n] = *(const bf16x8*)((const char*)Kl + swz(bo));
      }
#pragma unroll
      for (int m = 0; m < 2; ++m)
#pragma unroll
        for (int n = 0; n < 4; ++n)
          sacc[m][n] = __builtin_amdgcn_mfma_f32_16x16x32_bf16(q[m][kk], kf[n], sacc[m][n], 0, 0, 0);
    }

    // Online softmax (exp2 domain); row owned by 16 lanes (same l4 group).
#pragma unroll
    for (int m = 0; m < 2; ++m)
#pragma unroll
      for (int j = 0; j < 4; ++j) {
        float rm = fmaxf(fmaxf(sacc[m][0][j], sacc[m][1][j]),
                         fmaxf(sacc[m][2][j], sacc[m][3][j]));
#pragma unroll
        for (int off = 1; off < 16; off <<= 1) rm = fmaxf(rm, __shfl_xor(rm, off, 64));
        float mn = fmaxf(mst[m][j], rm);
        float corr = exp2f(mst[m][j] - mn);
        mst[m][j] = mn;
        float rs = 0.f;
#pragma unroll
        for (int n = 0; n < 4; ++n) {
          float p = exp2f(sacc[m][n][j] - mn);
          sacc[m][n][j] = p;
          rs += p;
        }
#pragma unroll
        for (int off = 1; off < 16; off <<= 1) rs += __shfl_xor(rs, off, 64);
        lst[m][j] = lst[m][j] * corr + rs;
#pragma unroll
        for (int n = 0; n < 4; ++n) oacc[m][n][j] *= corr;
      }

    // P (D-layout) -> LDS bf16 (swizzled, wave-private), re-read in A-frag layout.
    char* pb = (char*)Pl[w];
#pragma unroll
    for (int m = 0; m < 2; ++m)
#pragma unroll
      for (int n = 0; n < 4; ++n)
#pragma unroll
        for (int j = 0; j < 4; ++j) {
          int row = m * 16 + l4 * 4 + j;
          int bo = row * 128 + (n * 16 + l15) * 2;
          *(unsigned short*)(pb + swz(bo)) = f2bf(sacc[m][n][j]);
        }
    asm volatile("s_waitcnt lgkmcnt(0)" ::: "memory");

    // O += P @ V
#pragma unroll
    for (int kk = 0; kk < 2; ++kk) {
      bf16x8 pa[2], vf[4];
#pragma unroll
      for (int m = 0; m < 2; ++m) {
        int bo = (m * 16 + l15) * 128 + (kk * 32 + l4 * 8) * 2;
        pa[m] = *(const bf16x8*)(pb + swz(bo));
      }
#pragma unroll
      for (int n = 0; n < 4; ++n) {
        int bo = (n * 16 + l15) * 128 + (kk * 32 + l4 * 8) * 2;
        vf[n] = *(const bf16x8*)((const char*)Vt + swz(bo));
      }
#pragma unroll
      for (int m = 0; m < 2; ++m)
#pragma unroll
        for (int n = 0; n < 4; ++n)
          oacc[m][n] = __builtin_amdgcn_mfma_f32_16x16x32_bf16(pa[m], vf[n], oacc[m][n], 0, 0, 0);
    }
  }

  // Normalize + store bf16, head-major.
  unsigned short* op = ow + base + (size_t)hf * 128 * kDk;
#pragma unroll
  for (int m = 0; m < 2; ++m)
#pragma unroll
    for (int j = 0; j < 4; ++j) {
      float inv = 1.f / lst[m][j];
      int srow = w * 32 + m * 16 + l4 * 4 + j;
#pragma unroll
      for (int n = 0; n < 4; ++n)
        op[(size_t)srow * 64 + n * 16 + l15] = f2bf(oacc[m][n][j] * inv);
    }
}

}  // namespace

extern "C" void kernel_launch(void* const* d_in, const int* in_sizes, int n_in,
                              void* d_out, int out_size, void* d_ws, size_t ws_size,
                              hipStream_t stream) {
  const float* query = (const float*)d_in[0];
  const float* key   = (const float*)d_in[1];
  const float* value = (const float*)d_in[2];
  const float* Wq = (const float*)d_in[3];
  const float* bq = (const float*)d_in[4];
  const float* Wk = (const float*)d_in[5];
  const float* bk = (const float*)d_in[6];
  const float* Wv = (const float*)d_in[7];
  const float* bv = (const float*)d_in[8];
  const float* Wo = (const float*)d_in[9];
  const float* bo = (const float*)d_in[10];

  const float sQ = 0.125f * kLog2e;   // 1/sqrt(dk) * log2(e), folded into Q proj

  // ws (bf16 elems): Wq|Wk|Wv|Wo (4x1M) | qws|kws|vws head-major (3x16M)
  //   | path A extra: qbf|kbf|vbf row-major inputs (3x16M); aws aliases qbf.
  //   | path B: aws separate (16M).
  const size_t wsz = (size_t)kDm * kDm;          // 1M elems
  const size_t tsz = (size_t)kMr * kDm;          // 16M elems
  unsigned short* wsp = (unsigned short*)d_ws;
  unsigned short* wqb = wsp;
  unsigned short* wkb = wqb + wsz;
  unsigned short* wvb = wkb + wsz;
  unsigned short* wob = wvb + wsz;
  unsigned short* qws = wob + wsz;
  unsigned short* kws = qws + tsz;
  unsigned short* vws = kws + tsz;
  unsigned short* x0  = vws + tsz;               // path A: qbf/kbf/vbf; path B: aws

  const size_t needA = (4 * wsz + 6 * tsz) * 2;  // 200 MB
  const size_t needB = (4 * wsz + 4 * tsz) * 2;  // 136 MB
  if (ws_size < needB) return;

  cvt4<<<dim3(4096), dim3(256), 0, stream>>>(Wq, Wk, Wv, Wo, wqb);

  if (ws_size >= needA) {
    unsigned short* qbf = x0;
    unsigned short* kbf = qbf + tsz;
    unsigned short* vbf = kbf + tsz;
    unsigned short* aws = qbf;                   // reuse after q GEMM consumes qbf
    cvt_rm<<<dim3(16384), dim3(256), 0, stream>>>(query, qbf);
    cvt_rm<<<dim3(16384), dim3(256), 0, stream>>>(key,   kbf);
    cvt_rm<<<dim3(16384), dim3(256), 0, stream>>>(value, vbf);
    gemm_bt<0, 1><<<dim3(1024), 256, 0, stream>>>(qbf, wqb, bq, qws, sQ);
    gemm_bt<0, 1><<<dim3(1024), 256, 0, stream>>>(kbf, wkb, bk, kws, 1.0f);
    gemm_bt<0, 1><<<dim3(1024), 256, 0, stream>>>(vbf, wvb, bv, vws, 1.0f);
    attn_blkdiag<<<dim3(2048), 256, 0, stream>>>(qws, kws, vws, aws);
    gemm_bt<2, 0><<<dim3(1024), 256, 0, stream>>>(aws, wob, bo, d_out, 1.0f);
  } else {
    unsigned short* aws = x0;
    gemm_bt<1, 1><<<dim3(1024), 256, 0, stream>>>(query, wqb, bq, qws, sQ);
    gemm_bt<1, 1><<<dim3(1024), 256, 0, stream>>>(key,   wkb, bk, kws, 1.0f);
    gemm_bt<1, 1><<<dim3(1024), 256, 0, stream>>>(value, wvb, bv, vws, 1.0f);
    attn_blkdiag<<<dim3(2048), 256, 0, stream>>>(qws, kws, vws, aws);
    gemm_bt<2, 0><<<dim3(1024), 256, 0, stream>>>(aws, wob, bo, d_out, 1.0f);
  }
}

// Round 4
// 325.672 us; speedup vs baseline: 1.5455x; 1.1336x over previous
//
#include <hip/hip_runtime.h>
#include <hip/hip_bf16.h>

// MemoryEfficientMultiheadAttention: chunked (block-diagonal) MHA.
// S=4096, B=4, D=1024, H=16, dk=64, CHUNK=256.
// cvt(weights, qkv->bf16) -> fused QKV GEMM (head-major out, exp2-scaled Q)
//   -> flash attn (swapped QK^T, lane-local softmax, P-in-reg PV) -> out proj.

namespace {

constexpr int kSeq = 4096, kB = 4, kDm = 1024, kNh = 16, kDk = 64, kChk = 256;
constexpr int kMr = kSeq * kB;       // 16384 GEMM rows
constexpr float kLog2e = 1.44269504088896340736f;

typedef __attribute__((ext_vector_type(8))) short bf16x8;
typedef __attribute__((ext_vector_type(4))) short bf16x4;
typedef __attribute__((ext_vector_type(4))) float f32x4;
typedef __attribute__((ext_vector_type(8))) unsigned short u16x8;
typedef __attribute__((ext_vector_type(4))) unsigned short u16x4;

__device__ __forceinline__ unsigned short f2bf(float x) {
  union { float f; unsigned u; } v; v.f = x;
  unsigned r = v.u + 0x7fffu + ((v.u >> 16) & 1u);   // RNE
  return (unsigned short)(r >> 16);
}
// XOR swizzle for 128B-row-stride LDS tiles: xor byte bits 4-6 with row&7.
__device__ __forceinline__ int swz(int bo) { return bo ^ ((bo >> 3) & 0x70); }

__device__ __forceinline__ f32x4 mfma16x16(bf16x4 a, bf16x4 b, f32x4 c) {
#if __has_builtin(__builtin_amdgcn_mfma_f32_16x16x16bf16_1k)
  return __builtin_amdgcn_mfma_f32_16x16x16bf16_1k(a, b, c, 0, 0, 0);
#else
  asm volatile("v_mfma_f32_16x16x16_bf16 %0, %1, %2, %0\n\ts_nop 4"
               : "+v"(c) : "v"(a), "v"(b));
  return c;
#endif
}

// All four 1024x1024 weights -> bf16, dst contiguous (Wq|Wk|Wv|Wo).
__global__ __launch_bounds__(256) void cvt4(const float* __restrict__ s0,
                                            const float* __restrict__ s1,
                                            const float* __restrict__ s2,
                                            const float* __restrict__ s3,
                                            unsigned short* __restrict__ dst) {
  int i = blockIdx.x * 256 + threadIdx.x;          // 0 .. 4*2^18-1
  int t = i >> 18;
  int j = i & 0x3ffff;
  const float* s = (t == 0) ? s0 : (t == 1) ? s1 : (t == 2) ? s2 : s3;
  f32x4 v = *(const f32x4*)(s + (size_t)j * 4);
  u16x4 o;
  o[0] = f2bf(v[0]); o[1] = f2bf(v[1]); o[2] = f2bf(v[2]); o[3] = f2bf(v[3]);
  *(u16x4*)(dst + (size_t)i * 4) = o;
}

// query|key|value fp32 -> bf16, three contiguous 16M-elem tensors.
__global__ __launch_bounds__(256) void cvt3(const float* __restrict__ s0,
                                            const float* __restrict__ s1,
                                            const float* __restrict__ s2,
                                            unsigned short* __restrict__ dst) {
  size_t i = (size_t)blockIdx.x * 256 + threadIdx.x;   // 3 * 2^22 chunks
  int t = (int)(i >> 22);
  size_t j = i & 0x3fffff;
  const float* s = (t == 0) ? s0 : (t == 1) ? s1 : s2;
  f32x4 v = *(const f32x4*)(s + j * 4);
  u16x4 o;
  o[0] = f2bf(v[0]); o[1] = f2bf(v[1]); o[2] = f2bf(v[2]); o[3] = f2bf(v[3]);
  *(u16x4*)(dst + i * 4) = o;
}

// Fused QKV projection: C_mat = A_mat @ W_mat^T + b_mat, mat in {q,k,v}.
// Wcat = rows 0..3071 of (Wq|Wk|Wv), A per mat; out bf16 head-major, scaled.
// 128x128 tile, BK=32, 4 waves, 2-phase dbuf, XCD-swizzled grid (3072 blocks).
__global__ __launch_bounds__(256) void gemm_qkv(const unsigned short* __restrict__ qbf,
                                                const unsigned short* __restrict__ kbf,
                                                const unsigned short* __restrict__ vbf,
                                                const unsigned short* __restrict__ Wcat,
                                                const float* __restrict__ bq,
                                                const float* __restrict__ bk,
                                                const float* __restrict__ bv,
                                                unsigned short* __restrict__ dst,
                                                float sQ) {
  constexpr int K = kDm;
  __shared__ unsigned short As[2][128 * 32];
  __shared__ unsigned short Bs[2][128 * 32];
  const int tid = (int)threadIdx.x;
  const int l = tid & 63;
  const int wbase = tid & ~63;
  const int bid = (int)blockIdx.x;
  const int lin = (bid & 7) * 384 + (bid >> 3);    // bijective: 3072 % 8 == 0
  const int rbi = lin / 24, cbi = lin % 24;        // cb fastest: A-tile L2 reuse
  const int rb = rbi * 128;
  const int mat = cbi >> 3, ccol = (cbi & 7) * 128;
  const unsigned short* A = (mat == 0) ? qbf : (mat == 1) ? kbf : vbf;
  const float* bp = (mat == 0) ? bq : (mat == 1) ? bk : bv;
  const float scale = (mat == 0) ? sQ : 1.0f;
  unsigned short* out = dst + (size_t)mat * ((size_t)kMr * kDk * kNh / kNh) * 1; // tsz below
  out = dst + (size_t)mat * (size_t)kMr * kDm / 1;  // mat * 16M elems
  const int wr = ((tid >> 7) & 1) * 64;
  const int wc = ((tid >> 6) & 1) * 64;
  const int l15 = l & 15, l4 = l >> 4;

  f32x4 acc[4][4] = {};

  auto stage = [&](int buf, int k0) {
#pragma unroll
    for (int i = 0; i < 2; ++i) {
      int ch = i * 256 + tid;
      int rr = ch >> 2, cc = ch & 3;
      const unsigned short* g = A + (size_t)(rb + rr) * K + (k0 + cc * 8);
      __builtin_amdgcn_global_load_lds(
          (const __attribute__((address_space(1))) unsigned int*)g,
          (__attribute__((address_space(3))) unsigned int*)&As[buf][(i * 256 + wbase) * 8],
          16, 0, 0);
    }
#pragma unroll
    for (int i = 0; i < 2; ++i) {
      int ch = i * 256 + tid;
      int rr = ch >> 2, cc = ch & 3;
      const unsigned short* g = Wcat + (size_t)(cbi * 128 + rr) * K + (k0 + cc * 8);
      __builtin_amdgcn_global_load_lds(
          (const __attribute__((address_space(1))) unsigned int*)g,
          (__attribute__((address_space(3))) unsigned int*)&Bs[buf][(i * 256 + wbase) * 8],
          16, 0, 0);
    }
  };

  stage(0, 0);
  __syncthreads();
  int cur = 0;
  constexpr int nkt = K >> 5;
  for (int kt = 0; kt < nkt; ++kt) {
    if (kt + 1 < nkt) stage(cur ^ 1, (kt + 1) << 5);
    bf16x8 af[4], bfr[4];
#pragma unroll
    for (int m = 0; m < 4; ++m)
      af[m] = *(const bf16x8*)&As[cur][(wr + m * 16 + l15) * 32 + l4 * 8];
#pragma unroll
    for (int n = 0; n < 4; ++n)
      bfr[n] = *(const bf16x8*)&Bs[cur][(wc + n * 16 + l15) * 32 + l4 * 8];
#pragma unroll
    for (int m = 0; m < 4; ++m)
#pragma unroll
      for (int n = 0; n < 4; ++n)
        acc[m][n] = __builtin_amdgcn_mfma_f32_16x16x32_bf16(af[m], bfr[n], acc[m][n], 0, 0, 0);
    __syncthreads();
    cur ^= 1;
  }

  // Epilogue -> bf16 head-major (B,H,S,dk), rows t = s*kB + b.
#pragma unroll
  for (int n = 0; n < 4; ++n) {
    int col = ccol + wc + n * 16 + l15;
    float bvv = bp[col];
    int h = col >> 6, dd = col & 63;
#pragma unroll
    for (int m = 0; m < 4; ++m) {
      int row0 = rb + wr + m * 16 + l4 * 4;
#pragma unroll
      for (int j = 0; j < 4; ++j) {
        int t = row0 + j;
        int s = t >> 2, b2 = t & 3;
        out[((size_t)(b2 * kNh + h) * kSeq + s) * kDk + dd] =
            f2bf((acc[m][n][j] + bvv) * scale);
      }
    }
  }
}

// C = A @ Bw^T + bias (single matrix). Used for out-proj and the fallback path.
// ALAY: 1 = A fp32 row-major (reg-staged+cvt); 2 = A bf16 head-major.
// OHM:  1 = out bf16 head-major, scaled;  0 = out fp32 row-major.
template <int ALAY, int OHM>
__global__ __launch_bounds__(256) void gemm_bt(const void* __restrict__ Ap,
                                               const unsigned short* __restrict__ Bw,
                                               const float* __restrict__ bias,
                                               void* __restrict__ Cp, float scale) {
  constexpr int K = kDm, N = kDm;
  __shared__ unsigned short As[2][128 * 32];
  __shared__ unsigned short Bs[2][128 * 32];
  const int tid = (int)threadIdx.x;
  const int l = tid & 63;
  const int wbase = tid & ~63;
  const int bid = (int)blockIdx.x;
  const int lin = (bid & 7) * 128 + (bid >> 3);
  const int rb = (lin >> 3) * 128, cb = (lin & 7) * 128;
  const int wr = ((tid >> 7) & 1) * 64;
  const int wc = ((tid >> 6) & 1) * 64;
  const int l15 = l & 15, l4 = l >> 4;

  f32x4 acc[4][4] = {};

  auto stage = [&](int buf, int k0) {
    if constexpr (ALAY == 1) {
      const float* A = (const float*)Ap;
#pragma unroll
      for (int i = 0; i < 4; ++i) {
        int ci = tid + 256 * i;
        int rr = ci >> 3, c4 = ci & 7;
        f32x4 v = *(const f32x4*)(A + (size_t)(rb + rr) * K + (k0 + c4 * 4));
        u16x4 o;
        o[0] = f2bf(v[0]); o[1] = f2bf(v[1]); o[2] = f2bf(v[2]); o[3] = f2bf(v[3]);
        *(u16x4*)&As[buf][rr * 32 + c4 * 4] = o;
      }
    } else {
      const unsigned short* A = (const unsigned short*)Ap;
      int h = k0 >> 6, d0 = k0 & 63;
#pragma unroll
      for (int i = 0; i < 2; ++i) {
        int ch = i * 256 + tid;
        int rr = ch >> 2, cc = ch & 3;
        int t = rb + rr; int s = t >> 2, b2 = t & 3;
        const unsigned short* g =
            A + ((size_t)(b2 * kNh + h) * kSeq + s) * kDk + d0 + cc * 8;
        __builtin_amdgcn_global_load_lds(
            (const __attribute__((address_space(1))) unsigned int*)g,
            (__attribute__((address_space(3))) unsigned int*)&As[buf][(i * 256 + wbase) * 8],
            16, 0, 0);
      }
    }
#pragma unroll
    for (int i = 0; i < 2; ++i) {
      int ch = i * 256 + tid;
      int rr = ch >> 2, cc = ch & 3;
      const unsigned short* g = Bw + (size_t)(cb + rr) * K + (k0 + cc * 8);
      __builtin_amdgcn_global_load_lds(
          (const __attribute__((address_space(1))) unsigned int*)g,
          (__attribute__((address_space(3))) unsigned int*)&Bs[buf][(i * 256 + wbase) * 8],
          16, 0, 0);
    }
  };

  stage(0, 0);
  __syncthreads();
  int cur = 0;
  constexpr int nkt = K >> 5;
  for (int kt = 0; kt < nkt; ++kt) {
    if (kt + 1 < nkt) stage(cur ^ 1, (kt + 1) << 5);
    bf16x8 af[4], bfr[4];
#pragma unroll
    for (int m = 0; m < 4; ++m)
      af[m] = *(const bf16x8*)&As[cur][(wr + m * 16 + l15) * 32 + l4 * 8];
#pragma unroll
    for (int n = 0; n < 4; ++n)
      bfr[n] = *(const bf16x8*)&Bs[cur][(wc + n * 16 + l15) * 32 + l4 * 8];
#pragma unroll
    for (int m = 0; m < 4; ++m)
#pragma unroll
      for (int n = 0; n < 4; ++n)
        acc[m][n] = __builtin_amdgcn_mfma_f32_16x16x32_bf16(af[m], bfr[n], acc[m][n], 0, 0, 0);
    __syncthreads();
    cur ^= 1;
  }

#pragma unroll
  for (int n = 0; n < 4; ++n) {
    int col = cb + wc + n * 16 + l15;
    float bvv = bias[col];
    int h = col >> 6, dd = col & 63;
#pragma unroll
    for (int m = 0; m < 4; ++m) {
      int row0 = rb + wr + m * 16 + l4 * 4;
#pragma unroll
      for (int j = 0; j < 4; ++j) {
        float v = acc[m][n][j] + bvv;
        int t = row0 + j;
        if constexpr (OHM) {
          int s = t >> 2, b2 = t & 3;
          ((unsigned short*)Cp)[((size_t)(b2 * kNh + h) * kSeq + s) * kDk + dd] =
              f2bf(v * scale);
        } else {
          ((float*)Cp)[(size_t)t * N + col] = v;
        }
      }
    }
  }
}

// Block-diagonal flash attention, head-major (B*H, S, dk) in/out.
// Grid 2048: one block per (bh, chunk, half); 4 waves x 32 Q-rows.
// Swapped QK^T: S^T = mfma(K, Q) puts the softmax k-axis lane-local
// (q = lane&15, k = kn*16 + (lane>>4)*4 + j). P then feeds PV directly as
// the A-fragment of v_mfma_f32_16x16x16_bf16 (k granularity 4) - no P LDS.
__global__ __launch_bounds__(256) void attn_blkdiag(const unsigned short* __restrict__ qw,
                                                    const unsigned short* __restrict__ kw,
                                                    const unsigned short* __restrict__ vw,
                                                    unsigned short* __restrict__ ow) {
  __shared__ unsigned short Kl[64 * 64];       // [kv_row][d]   (swizzled)
  __shared__ unsigned short Vt[64 * 64];       // [d][kv_row]   (transposed, swizzled)
  const int tid = (int)threadIdx.x;
  const int w = tid >> 6, l = tid & 63;
  const int l15 = l & 15, l4 = l >> 4;
  const int bid0 = (int)blockIdx.x;
  const int bid = (bid0 & 7) * 256 + (bid0 >> 3);   // XCD swizzle, 2048 % 8 == 0
  const int hf = bid & 1, c = (bid >> 1) & 15, bh = bid >> 5;
  const size_t base = ((size_t)bh * kSeq + c * kChk) * kDk;
  const unsigned short* qp = qw + base + (size_t)hf * 128 * kDk;
  const unsigned short* kp = kw + base;
  const unsigned short* vp = vw + base;

  // Q B-fragments (row = q = m*16+l15, d-slice = kk*32 + l4*8). Scale folded.
  bf16x8 q[2][2];
#pragma unroll
  for (int m = 0; m < 2; ++m)
#pragma unroll
    for (int kk = 0; kk < 2; ++kk)
      q[m][kk] = *(const bf16x8*)(qp + (w * 32 + m * 16 + l15) * 64 + kk * 32 + l4 * 8);

  float mst[2] = {-1e30f, -1e30f}, lst[2] = {0.f, 0.f};
  f32x4 oacc[2][4] = {};

  // Coalesced KV prefetch: each thread owns 32B of the contiguous 8KB tile.
  const int r = tid >> 2, c0 = (tid & 3) * 16;
  u16x8 kr0, kr1, vr0, vr1;
  {
    const unsigned short* kt = kp + tid * 16;
    kr0 = *(const u16x8*)kt; kr1 = *(const u16x8*)(kt + 8);
    const unsigned short* vt = vp + tid * 16;
    vr0 = *(const u16x8*)vt; vr1 = *(const u16x8*)(vt + 8);
  }

  for (int kb = 0; kb < 4; ++kb) {
    __syncthreads();   // previous iteration's K/Vt reads are done
    {
      int bo = r * 128 + c0 * 2;
      *(u16x8*)((char*)Kl + swz(bo)) = kr0;
      *(u16x8*)((char*)Kl + swz(bo + 16)) = kr1;
#pragma unroll
      for (int j = 0; j < 8; ++j) {
        *(unsigned short*)((char*)Vt + swz((c0 + j) * 128 + r * 2)) = vr0[j];
        *(unsigned short*)((char*)Vt + swz((c0 + 8 + j) * 128 + r * 2)) = vr1[j];
      }
    }
    __syncthreads();
    if (kb < 3) {   // T14: issue next-tile loads; latency hides under compute
      const unsigned short* kt = kp + (kb + 1) * (64 * kDk) + tid * 16;
      kr0 = *(const u16x8*)kt; kr1 = *(const u16x8*)(kt + 8);
      const unsigned short* vt = vp + (kb + 1) * (64 * kDk) + tid * 16;
      vr0 = *(const u16x8*)vt; vr1 = *(const u16x8*)(vt + 8);
    }

    // S^T = K Q^T: sacc[kn][m][j] = S[q = m*16+l15][kv = kn*16 + l4*4 + j]
    f32x4 sacc[4][2] = {};
    __builtin_amdgcn_s_setprio(1);
#pragma unroll
    for (int kk = 0; kk < 2; ++kk) {
      bf16x8 kf[4];
#pragma unroll
      for (int kn = 0; kn < 4; ++kn) {
        int bo = (kn * 16 + l15) * 128 + (kk * 32 + l4 * 8) * 2;
        kf[kn] = *(const bf16x8*)((const char*)Kl + swz(bo));
      }
#pragma unroll
      for (int kn = 0; kn < 4; ++kn)
#pragma unroll
        for (int m = 0; m < 2; ++m)
          sacc[kn][m] = __builtin_amdgcn_mfma_f32_16x16x32_bf16(kf[kn], q[m][kk], sacc[kn][m], 0, 0, 0);
    }
    __builtin_amdgcn_s_setprio(0);

    // Lane-local online softmax (exp2 domain) + pack P for PV A-frags.
    unsigned pw[2][4][2];
    float cbq[2][4];
#pragma unroll
    for (int m = 0; m < 2; ++m) {
      float rm = -1e30f;
#pragma unroll
      for (int kn = 0; kn < 4; ++kn)
#pragma unroll
        for (int j = 0; j < 4; ++j) rm = fmaxf(rm, sacc[kn][m][j]);
      rm = fmaxf(rm, __shfl_xor(rm, 16, 64));
      rm = fmaxf(rm, __shfl_xor(rm, 32, 64));
      float mn = fmaxf(mst[m], rm);
      float corr = exp2f(mst[m] - mn);
      mst[m] = mn;
      float rs = 0.f;
#pragma unroll
      for (int kn = 0; kn < 4; ++kn) {
#pragma unroll
        for (int j = 0; j < 4; ++j) {
          float p = exp2f(sacc[kn][m][j] - mn);
          sacc[kn][m][j] = p;
          rs += p;
        }
        pw[m][kn][0] = (unsigned)f2bf(sacc[kn][m][0]) | ((unsigned)f2bf(sacc[kn][m][1]) << 16);
        pw[m][kn][1] = (unsigned)f2bf(sacc[kn][m][2]) | ((unsigned)f2bf(sacc[kn][m][3]) << 16);
      }
      rs += __shfl_xor(rs, 16, 64);
      rs += __shfl_xor(rs, 32, 64);
      lst[m] = lst[m] * corr + rs;
      // corr lives at q=l15; oacc rows are q = l4*4+j -> broadcast.
#pragma unroll
      for (int j = 0; j < 4; ++j) cbq[m][j] = __shfl(corr, l4 * 4 + j, 64);
#pragma unroll
      for (int n = 0; n < 4; ++n)
#pragma unroll
        for (int j = 0; j < 4; ++j) oacc[m][n][j] *= cbq[m][j];
    }

    // O += P @ V via 16x16x16 MFMA: P direct from registers, V^T from LDS (b64).
    __builtin_amdgcn_s_setprio(1);
#pragma unroll
    for (int kn = 0; kn < 4; ++kn) {
      bf16x4 vf[4];
#pragma unroll
      for (int n = 0; n < 4; ++n) {
        int bo = (n * 16 + l15) * 128 + (kn * 16 + l4 * 4) * 2;
        vf[n] = *(const bf16x4*)((const char*)Vt + swz(bo));
      }
#pragma unroll
      for (int m = 0; m < 2; ++m) {
        union { unsigned u[2]; bf16x4 h; } pk;
        pk.u[0] = pw[m][kn][0]; pk.u[1] = pw[m][kn][1];
#pragma unroll
        for (int n = 0; n < 4; ++n)
          oacc[m][n] = mfma16x16(pk.h, vf[n], oacc[m][n]);
      }
    }
    __builtin_amdgcn_s_setprio(0);
  }

  // Normalize + store bf16, head-major. lst lives at q=l15 -> broadcast to rows.
  unsigned short* op = ow + base + (size_t)hf * 128 * kDk;
#pragma unroll
  for (int m = 0; m < 2; ++m) {
    float inv = 1.f / lst[m];
#pragma unroll
    for (int j = 0; j < 4; ++j) {
      float ib = __shfl(inv, l4 * 4 + j, 64);
      int srow = w * 32 + m * 16 + l4 * 4 + j;
#pragma unroll
      for (int n = 0; n < 4; ++n)
        op[(size_t)srow * 64 + n * 16 + l15] = f2bf(oacc[m][n][j] * ib);
    }
  }
}

}  // namespace

extern "C" void kernel_launch(void* const* d_in, const int* in_sizes, int n_in,
                              void* d_out, int out_size, void* d_ws, size_t ws_size,
                              hipStream_t stream) {
  const float* query = (const float*)d_in[0];
  const float* key   = (const float*)d_in[1];
  const float* value = (const float*)d_in[2];
  const float* Wq = (const float*)d_in[3];
  const float* bq = (const float*)d_in[4];
  const float* Wk = (const float*)d_in[5];
  const float* bk = (const float*)d_in[6];
  const float* Wv = (const float*)d_in[7];
  const float* bv = (const float*)d_in[8];
  const float* Wo = (const float*)d_in[9];
  const float* bo = (const float*)d_in[10];

  const float sQ = 0.125f * kLog2e;   // 1/sqrt(dk) * log2(e), folded into Q proj

  const size_t wsz = (size_t)kDm * kDm;          // 1M elems
  const size_t tsz = (size_t)kMr * kDm;          // 16M elems
  unsigned short* wsp = (unsigned short*)d_ws;
  unsigned short* wqb = wsp;                     // Wq|Wk|Wv|Wo contiguous
  unsigned short* wob = wqb + 3 * wsz;
  unsigned short* qws = wqb + 4 * wsz;
  unsigned short* kws = qws + tsz;
  unsigned short* vws = kws + tsz;
  unsigned short* x0  = vws + tsz;               // path A: qbf|kbf|vbf; path B: aws

  const size_t needA = (4 * wsz + 6 * tsz) * 2;  // 200 MB
  const size_t needB = (4 * wsz + 4 * tsz) * 2;  // 136 MB
  if (ws_size < needB) return;

  cvt4<<<dim3(4096), dim3(256), 0, stream>>>(Wq, Wk, Wv, Wo, wqb);

  if (ws_size >= needA) {
    unsigned short* qbf = x0;
    unsigned short* kbf = qbf + tsz;
    unsigned short* vbf = kbf + tsz;
    unsigned short* aws = qbf;                   // reuse after QKV GEMM consumes qbf
    cvt3<<<dim3(49152), dim3(256), 0, stream>>>(query, key, value, qbf);
    gemm_qkv<<<dim3(3072), 256, 0, stream>>>(qbf, kbf, vbf, wqb, bq, bk, bv, qws, sQ);
    attn_blkdiag<<<dim3(2048), 256, 0, stream>>>(qws, kws, vws, aws);
    gemm_bt<2, 0><<<dim3(1024), 256, 0, stream>>>(aws, wob, bo, d_out, 1.0f);
  } else {
    unsigned short* aws = x0;
    gemm_bt<1, 1><<<dim3(1024), 256, 0, stream>>>(query, wqb, bq, qws, sQ);
    gemm_bt<1, 1><<<dim3(1024), 256, 0, stream>>>(key,   wqb + wsz, bk, kws, 1.0f);
    gemm_bt<1, 1><<<dim3(1024), 256, 0, stream>>>(value, wqb + 2 * wsz, bv, vws, 1.0f);
    attn_blkdiag<<<dim3(2048), 256, 0, stream>>>(qws, kws, vws, aws);
    gemm_bt<2, 0><<<dim3(1024), 256, 0, stream>>>(aws, wob, bo, d_out, 1.0f);
  }
}